// Round 5
// baseline (201.307 us; speedup 1.0000x reference)
//
#include <hip/hip_runtime.h>

#define N_NODES 65536
#define B_G     64
#define NPG     1024
#define KC      128
#define DIN     128
#define E_EDGES 1048576
#define EPG     16384
#define NSLICE  8
#define SLICE_E (EPG / NSLICE)    // 2048 edges per slice
#define CSTRIDE (EPG + NPG)       // per-graph CSR slots (even-padded offsets)

typedef __attribute__((ext_vector_type(8))) short short8;
typedef __attribute__((ext_vector_type(4))) float floatx4;

static __device__ __forceinline__ short f2bf(float x) {
    unsigned u = __float_as_uint(x);
    unsigned r = (u + 0x7FFF + ((u >> 16) & 1)) >> 16;
    return (short)r;
}
static __device__ __forceinline__ unsigned pack2(float a, float b) {
    return (unsigned)(unsigned short)f2bf(a) | ((unsigned)(unsigned short)f2bf(b) << 16);
}

// ================ setup_a: blocks 0..511 = per-(graph,slice) degree histogram;
//                  blocks 512.. = wt / feaT / h_bf conversions
__global__ __launch_bounds__(256) void setup_a(
    const float* __restrict__ Wself, const float* __restrict__ Wneigh,
    const float* __restrict__ fea, const float* __restrict__ h,
    const int* __restrict__ edst,
    short* __restrict__ wt, short* __restrict__ feaT, short* __restrict__ h_bf,
    int* __restrict__ slicecnt)
{
    int bid = blockIdx.x;
    int tid = threadIdx.x;
    if (bid < B_G * NSLICE) {
        __shared__ int cnt[NPG];
        int g = bid >> 3, s = bid & 7;
        int gbase = g << 10;
        for (int i = tid; i < NPG; i += 256) cnt[i] = 0;
        __syncthreads();
        const int* ed = edst + (size_t)g * EPG + s * SLICE_E;
#pragma unroll
        for (int it = 0; it < SLICE_E / 256; it++)
            atomicAdd(&cnt[ed[it * 256 + tid] - gbase], 1);
        __syncthreads();
        int* sc = slicecnt + ((size_t)bid << 10);
        for (int i = tid; i < NPG; i += 256) sc[i] = cnt[i];
    } else {
        long idx = (long)(bid - B_G * NSLICE) * 256 + tid;
        if (idx < 32768) {
            int n = (int)(idx >> 8), k = (int)(idx & 255);
            float v = (k < 128) ? Wself[k * 128 + n] : Wneigh[(k - 128) * 128 + n];
            wt[idx] = f2bf(v);
        } else if (idx < 32768 + 1048576) {
            long fi = idx - 32768;
            int g = (int)(fi >> 14), d = (int)((fi >> 7) & 127), k = (int)(fi & 127);
            feaT[fi] = f2bf(fea[((long)g * 128 + k) * 128 + d]);
        } else {
            long gi = idx - 32768 - 1048576;   // 8 floats per item
            const float4* hp = (const float4*)h + gi * 2;
            float4 a = hp[0], b4 = hp[1];
            uint4 w;
            w.x = pack2(a.x, a.y);
            w.y = pack2(a.z, a.w);
            w.z = pack2(b4.x, b4.y);
            w.w = pack2(b4.z, b4.w);
            ((uint4*)h_bf)[gi] = w;
        }
    }
}

// ================ setup_b: per-graph scan -> offs, deg, per-slice bases
__global__ __launch_bounds__(1024) void setup_b(
    const int* __restrict__ slicecnt, int* __restrict__ offs,
    int* __restrict__ deg, int* __restrict__ sliceoffs)
{
    __shared__ int sa[NPG];
    int g = blockIdx.x;
    int tid = threadIdx.x;
    int s8[NSLICE];
    int d = 0;
#pragma unroll
    for (int s = 0; s < NSLICE; s++) {
        s8[s] = slicecnt[(((size_t)g * NSLICE + s) << 10) + tid];
        d += s8[s];
    }
    int p = (d + 1) & ~1;
    sa[tid] = p;
    __syncthreads();
    for (int off = 1; off < NPG; off <<= 1) {
        int v = sa[tid];
        int vv = (tid >= off) ? sa[tid - off] : 0;
        __syncthreads();
        sa[tid] = v + vv;
        __syncthreads();
    }
    int excl = sa[tid] - p;
    offs[(g << 10) + tid] = excl;
    deg[(g << 10) + tid] = d;
    int run = excl;
#pragma unroll
    for (int s = 0; s < NSLICE; s++) {
        sliceoffs[(((size_t)g * NSLICE + s) << 10) + tid] = run;
        run += s8[s];
    }
}

// ================ setup_c: per-(graph,slice) scatter into CSR
__global__ __launch_bounds__(256) void setup_c(
    const int* __restrict__ esrc, const int* __restrict__ edst,
    const int* __restrict__ sliceoffs, unsigned short* __restrict__ csr)
{
    __shared__ int cur[NPG];
    int bid = blockIdx.x;
    int tid = threadIdx.x;
    int g = bid >> 3, s = bid & 7;
    int gbase = g << 10;
    const int* so = sliceoffs + ((size_t)bid << 10);
    for (int i = tid; i < NPG; i += 256) cur[i] = so[i];
    __syncthreads();
    const int* ed = edst + (size_t)g * EPG + s * SLICE_E;
    const int* es = esrc + (size_t)g * EPG + s * SLICE_E;
    unsigned short* cg = csr + (size_t)g * CSTRIDE;
#pragma unroll
    for (int it = 0; it < SLICE_E / 256; it++) {
        int e = it * 256 + tid;
        int d = ed[e] - gbase;
        int src = es[e] - gbase;
        int pos = atomicAdd(&cur[d], 1);
        cg[pos] = (unsigned short)src;
    }
}

// ================ aggregation (pull, bf16): one wave per node,
// 2 edges per gather instruction (lanes 0-31 edge A, 32-63 edge B).
// Block mapping: consecutive blocks work the SAME graph so each XCD's L2
// holds only a few graphs' h_bf (256 KB each) at a time.
__global__ __launch_bounds__(256) void agg_kernel(
    const short* __restrict__ h_bf, const unsigned short* __restrict__ csr,
    const int* __restrict__ offs, const int* __restrict__ deg,
    short* __restrict__ neigh)
{
    int g = blockIdx.x >> 8;          // 256 chunks per graph, contiguous
    int chunk = blockIdx.x & 255;
    int wave = threadIdx.x >> 6, lane = threadIdx.x & 63;
    int local = chunk * 4 + wave;
    int node = g * NPG + local;
    int start = offs[node];
    int m = deg[node];
    const unsigned short* lst = csr + (size_t)g * CSTRIDE + start;
    const uint2* rows = (const uint2*)h_bf + (size_t)g * NPG * 32;  // 32 uint2 / row
    int l31 = lane & 31;
    int hi = lane >> 5;
    float s0 = 0.f, s1 = 0.f, s2 = 0.f, s3 = 0.f;
    int pairs = m >> 1;
    int p = 0;
    for (; p + 4 <= pairs; p += 4) {
        unsigned pp[4];
#pragma unroll
        for (int u = 0; u < 4; u++) pp[u] = *(const unsigned*)(lst + 2 * (p + u));
        uint2 v[4];
#pragma unroll
        for (int u = 0; u < 4; u++) {
            int s = hi ? (int)(pp[u] >> 16) : (int)(pp[u] & 0xffff);
            v[u] = rows[s * 32 + l31];
        }
#pragma unroll
        for (int u = 0; u < 4; u++) {
            s0 += __uint_as_float(v[u].x << 16);
            s1 += __uint_as_float(v[u].x & 0xffff0000u);
            s2 += __uint_as_float(v[u].y << 16);
            s3 += __uint_as_float(v[u].y & 0xffff0000u);
        }
    }
    for (; p < pairs; p++) {
        unsigned pp = *(const unsigned*)(lst + 2 * p);
        int s = hi ? (int)(pp >> 16) : (int)(pp & 0xffff);
        uint2 vv = rows[s * 32 + l31];
        s0 += __uint_as_float(vv.x << 16);
        s1 += __uint_as_float(vv.x & 0xffff0000u);
        s2 += __uint_as_float(vv.y << 16);
        s3 += __uint_as_float(vv.y & 0xffff0000u);
    }
    if (m & 1) {
        int s = lst[m - 1];
        if (!hi) {
            uint2 vv = rows[s * 32 + l31];
            s0 += __uint_as_float(vv.x << 16);
            s1 += __uint_as_float(vv.x & 0xffff0000u);
            s2 += __uint_as_float(vv.y << 16);
            s3 += __uint_as_float(vv.y & 0xffff0000u);
        }
    }
    s0 += __shfl_xor(s0, 32, 64);
    s1 += __shfl_xor(s1, 32, 64);
    s2 += __shfl_xor(s2, 32, 64);
    s3 += __shfl_xor(s3, 32, 64);
    if (!hi) {
        float invd = 1.0f / fmaxf((float)m, 1.0f);
        uint2 w;
        w.x = pack2(s0 * invd, s1 * invd);
        w.y = pack2(s2 * invd, s3 * invd);
        ((uint2*)neigh)[(size_t)node * 32 + l31] = w;
    }
}

// ================ fused, barrier-free, 64-row tiles (1024 blocks for occupancy):
//   A and B MFMA fragments load DIRECTLY from global (16B contiguous each);
//   wt (64 KB) and feaT (32 KB/graph) are L2/L1-resident across blocks.
//   Only P goes through LDS (per-wave-private rows -> no __syncthreads).
__global__ __launch_bounds__(256) void fused_kernel(
    const short* __restrict__ h_bf, const short* __restrict__ neigh,
    const short* __restrict__ wt, const float* __restrict__ bias,
    const short* __restrict__ feaT, float* __restrict__ out)
{
    __shared__ __align__(16) short ldsP[64 * 132];   // 16.9 KB

    int tid = threadIdx.x;
    int tile_m = blockIdx.x * 64;
    int g = tile_m >> 10;
    int wave = tid >> 6, lane = tid & 63;
    int l15 = lane & 15, quad = lane >> 4;

    floatx4 zz = {0.f, 0.f, 0.f, 0.f};
    floatx4 acc[8];
#pragma unroll
    for (int j = 0; j < 8; j++) acc[j] = zz;

    // ---- GEMM1: logits = [h_bf | neigh] @ wt^T, K=256, all operands direct-global
#pragma unroll
    for (int kk = 0; kk < 4; kk++) {
#pragma unroll
        for (int ks = 0; ks < 2; ks++) {
            int colk = kk * 64 + ks * 32 + quad * 8;
            int m = tile_m + wave * 16 + l15;
            short8 af = (kk < 2)
                ? *reinterpret_cast<const short8*>(h_bf + (size_t)m * DIN + colk)
                : *reinterpret_cast<const short8*>(neigh + (size_t)m * DIN + (colk - 128));
#pragma unroll
            for (int cb = 0; cb < 8; cb++) {
                int n = cb * 16 + l15;
                short8 bf = *reinterpret_cast<const short8*>(wt + n * 256 + colk);
                acc[cb] = __builtin_amdgcn_mfma_f32_16x16x32_bf16(af, bf, acc[cb], 0, 0, 0);
            }
        }
    }

    // ---- softmax(relu(+bias)) in regs; P -> ldsP (bf16, stride 132)
    float bv[8];
#pragma unroll
    for (int cb = 0; cb < 8; cb++) bv[cb] = bias[cb * 16 + l15];

#pragma unroll
    for (int v = 0; v < 4; v++) {
        float x[8];
        float m = -1e30f;
#pragma unroll
        for (int cb = 0; cb < 8; cb++) {
            float t = acc[cb][v] + bv[cb];
            t = fmaxf(t, 0.f);
            x[cb] = t;
            m = fmaxf(m, t);
        }
#pragma unroll
        for (int off = 1; off < 16; off <<= 1) m = fmaxf(m, __shfl_xor(m, off, 64));
        float s = 0.f;
#pragma unroll
        for (int cb = 0; cb < 8; cb++) { x[cb] = __expf(x[cb] - m); s += x[cb]; }
#pragma unroll
        for (int off = 1; off < 16; off <<= 1) s += __shfl_xor(s, off, 64);
        float inv = 1.0f / s;
        int row = wave * 16 + quad * 4 + v;   // local row (wave-private)
#pragma unroll
        for (int cb = 0; cb < 8; cb++)
            ldsP[row * 132 + cb * 16 + l15] = f2bf(x[cb] * inv);
    }

    // wave-private P rows: drain this wave's LDS writes, no block barrier needed
    asm volatile("s_waitcnt lgkmcnt(0)" ::: "memory");

    // ---- GEMM2: out = P @ fea[g], B direct-global (feaT L2-resident)
    floatx4 oacc[8];
#pragma unroll
    for (int j = 0; j < 8; j++) oacc[j] = zz;

    short8 pf[4];
#pragma unroll
    for (int ks = 0; ks < 4; ks++)
        pf[ks] = *reinterpret_cast<const short8*>(
            ldsP + (wave * 16 + l15) * 132 + ks * 32 + quad * 8);

#pragma unroll
    for (int cb = 0; cb < 8; cb++) {
#pragma unroll
        for (int ks = 0; ks < 4; ks++) {
            short8 bf = *reinterpret_cast<const short8*>(
                feaT + ((size_t)g * 128 + cb * 16 + l15) * 128 + ks * 32 + quad * 8);
            oacc[cb] = __builtin_amdgcn_mfma_f32_16x16x32_bf16(pf[ks], bf, oacc[cb], 0, 0, 0);
        }
    }

#pragma unroll
    for (int v = 0; v < 4; v++) {
        int row = tile_m + wave * 16 + quad * 4 + v;
#pragma unroll
        for (int cb = 0; cb < 8; cb++)
            out[(size_t)row * 128 + cb * 16 + l15] = oacc[cb][v];
    }
}

extern "C" void kernel_launch(void* const* d_in, const int* in_sizes, int n_in,
                              void* d_out, int out_size, void* d_ws, size_t ws_size,
                              hipStream_t stream) {
    const float* h      = (const float*)d_in[0];
    const float* fea    = (const float*)d_in[1];
    const float* Wself  = (const float*)d_in[2];
    const float* Wneigh = (const float*)d_in[3];
    const float* bias   = (const float*)d_in[4];
    const int*   esrc   = (const int*)d_in[5];
    const int*   edst   = (const int*)d_in[6];
    float* out = (float*)d_out;

    char* ws = (char*)d_ws;
    short* h_bf = (short*)ws;
    size_t off = (size_t)N_NODES * DIN * sizeof(short);                       // 16 MB
    short* neigh = (short*)(ws + off); off += (size_t)N_NODES * DIN * sizeof(short);   // 16 MB
    short* wt    = (short*)(ws + off); off += (size_t)128 * 256 * sizeof(short);       // 64 KB
    short* feaT  = (short*)(ws + off); off += (size_t)B_G * 128 * 128 * sizeof(short); // 2 MB
    unsigned short* csr = (unsigned short*)(ws + off); off += (size_t)B_G * CSTRIDE * sizeof(short); // 2.2 MB
    int* offs = (int*)(ws + off); off += (size_t)N_NODES * sizeof(int);       // 256 KB
    int* deg  = (int*)(ws + off); off += (size_t)N_NODES * sizeof(int);       // 256 KB
    int* slicecnt  = (int*)(ws + off); off += (size_t)B_G * NSLICE * NPG * sizeof(int); // 2 MB
    int* sliceoffs = (int*)(ws + off);                                        // 2 MB

    // setup_a grid: 512 hist blocks + (32768 + 1048576 + 1048576)/256 = 8320 conv blocks
    setup_a<<<B_G * NSLICE + 8320, 256, 0, stream>>>(Wself, Wneigh, fea, h, edst,
                                                     wt, feaT, h_bf, slicecnt);
    setup_b<<<B_G, 1024, 0, stream>>>(slicecnt, offs, deg, sliceoffs);
    setup_c<<<B_G * NSLICE, 256, 0, stream>>>(esrc, edst, sliceoffs, csr);
    agg_kernel<<<256 * B_G, 256, 0, stream>>>(h_bf, csr, offs, deg, neigh);
    fused_kernel<<<N_NODES / 64, 256, 0, stream>>>(h_bf, neigh, wt, bias, feaT, out);
}

// Round 6
// 198.205 us; speedup vs baseline: 1.0156x; 1.0156x over previous
//
#include <hip/hip_runtime.h>

#define N_NODES 65536
#define B_G     64
#define NPG     1024
#define KC      128
#define DIN     128
#define E_EDGES 1048576
#define EPG     16384
#define NSLICE  8
#define SLICE_E (EPG / NSLICE)    // 2048 edges per slice
#define CSTRIDE (EPG + NPG)       // per-graph CSR slots (even-padded offsets)

typedef __attribute__((ext_vector_type(8))) short short8;
typedef __attribute__((ext_vector_type(4))) float floatx4;

static __device__ __forceinline__ short f2bf(float x) {
    unsigned u = __float_as_uint(x);
    unsigned r = (u + 0x7FFF + ((u >> 16) & 1)) >> 16;
    return (short)r;
}
static __device__ __forceinline__ unsigned pack2(float a, float b) {
    return (unsigned)(unsigned short)f2bf(a) | ((unsigned)(unsigned short)f2bf(b) << 16);
}

// ================ setup_a: blocks 0..511 = per-(graph,slice) degree histogram;
//                  blocks 512.. = wt / feaT / h_bf conversions
__global__ __launch_bounds__(256) void setup_a(
    const float* __restrict__ Wself, const float* __restrict__ Wneigh,
    const float* __restrict__ fea, const float* __restrict__ h,
    const int* __restrict__ edst,
    short* __restrict__ wt, short* __restrict__ feaT, short* __restrict__ h_bf,
    int* __restrict__ slicecnt)
{
    int bid = blockIdx.x;
    int tid = threadIdx.x;
    if (bid < B_G * NSLICE) {
        __shared__ int cnt[NPG];
        int g = bid >> 3, s = bid & 7;
        int gbase = g << 10;
        for (int i = tid; i < NPG; i += 256) cnt[i] = 0;
        __syncthreads();
        const int* ed = edst + (size_t)g * EPG + s * SLICE_E;
#pragma unroll
        for (int it = 0; it < SLICE_E / 256; it++)
            atomicAdd(&cnt[ed[it * 256 + tid] - gbase], 1);
        __syncthreads();
        int* sc = slicecnt + ((size_t)bid << 10);
        for (int i = tid; i < NPG; i += 256) sc[i] = cnt[i];
    } else {
        long idx = (long)(bid - B_G * NSLICE) * 256 + tid;
        if (idx < 32768) {
            int n = (int)(idx >> 8), k = (int)(idx & 255);
            float v = (k < 128) ? Wself[k * 128 + n] : Wneigh[(k - 128) * 128 + n];
            wt[idx] = f2bf(v);
        } else if (idx < 32768 + 1048576) {
            long fi = idx - 32768;
            int g = (int)(fi >> 14), d = (int)((fi >> 7) & 127), k = (int)(fi & 127);
            feaT[fi] = f2bf(fea[((long)g * 128 + k) * 128 + d]);
        } else {
            long gi = idx - 32768 - 1048576;   // 8 floats per item
            const float4* hp = (const float4*)h + gi * 2;
            float4 a = hp[0], b4 = hp[1];
            uint4 w;
            w.x = pack2(a.x, a.y);
            w.y = pack2(a.z, a.w);
            w.z = pack2(b4.x, b4.y);
            w.w = pack2(b4.z, b4.w);
            ((uint4*)h_bf)[gi] = w;
        }
    }
}

// ================ setup_b: per-graph scan -> offs, deg, per-slice bases
__global__ __launch_bounds__(1024) void setup_b(
    const int* __restrict__ slicecnt, int* __restrict__ offs,
    int* __restrict__ deg, int* __restrict__ sliceoffs)
{
    __shared__ int sa[NPG];
    int g = blockIdx.x;
    int tid = threadIdx.x;
    int s8[NSLICE];
    int d = 0;
#pragma unroll
    for (int s = 0; s < NSLICE; s++) {
        s8[s] = slicecnt[(((size_t)g * NSLICE + s) << 10) + tid];
        d += s8[s];
    }
    int p = (d + 1) & ~1;
    sa[tid] = p;
    __syncthreads();
    for (int off = 1; off < NPG; off <<= 1) {
        int v = sa[tid];
        int vv = (tid >= off) ? sa[tid - off] : 0;
        __syncthreads();
        sa[tid] = v + vv;
        __syncthreads();
    }
    int excl = sa[tid] - p;
    offs[(g << 10) + tid] = excl;
    deg[(g << 10) + tid] = d;
    int run = excl;
#pragma unroll
    for (int s = 0; s < NSLICE; s++) {
        sliceoffs[(((size_t)g * NSLICE + s) << 10) + tid] = run;
        run += s8[s];
    }
}

// ================ setup_c: per-(graph,slice) scatter into CSR
__global__ __launch_bounds__(256) void setup_c(
    const int* __restrict__ esrc, const int* __restrict__ edst,
    const int* __restrict__ sliceoffs, unsigned short* __restrict__ csr)
{
    __shared__ int cur[NPG];
    int bid = blockIdx.x;
    int tid = threadIdx.x;
    int g = bid >> 3, s = bid & 7;
    int gbase = g << 10;
    const int* so = sliceoffs + ((size_t)bid << 10);
    for (int i = tid; i < NPG; i += 256) cur[i] = so[i];
    __syncthreads();
    const int* ed = edst + (size_t)g * EPG + s * SLICE_E;
    const int* es = esrc + (size_t)g * EPG + s * SLICE_E;
    unsigned short* cg = csr + (size_t)g * CSTRIDE;
#pragma unroll
    for (int it = 0; it < SLICE_E / 256; it++) {
        int e = it * 256 + tid;
        int d = ed[e] - gbase;
        int src = es[e] - gbase;
        int pos = atomicAdd(&cur[d], 1);
        cg[pos] = (unsigned short)src;
    }
}

// ================ aggregation (pull, bf16): one wave per node,
// 2 edges per gather instruction (lanes 0-31 edge A, 32-63 edge B).
__global__ __launch_bounds__(256) void agg_kernel(
    const short* __restrict__ h_bf, const unsigned short* __restrict__ csr,
    const int* __restrict__ offs, const int* __restrict__ deg,
    short* __restrict__ neigh)
{
    int g = blockIdx.x >> 8;          // 256 chunks per graph, contiguous
    int chunk = blockIdx.x & 255;
    int wave = threadIdx.x >> 6, lane = threadIdx.x & 63;
    int local = chunk * 4 + wave;
    int node = g * NPG + local;
    int start = offs[node];
    int m = deg[node];
    const unsigned short* lst = csr + (size_t)g * CSTRIDE + start;
    const uint2* rows = (const uint2*)h_bf + (size_t)g * NPG * 32;  // 32 uint2 / row
    int l31 = lane & 31;
    int hi = lane >> 5;
    float s0 = 0.f, s1 = 0.f, s2 = 0.f, s3 = 0.f;
    int pairs = m >> 1;
    int p = 0;
    for (; p + 4 <= pairs; p += 4) {
        unsigned pp[4];
#pragma unroll
        for (int u = 0; u < 4; u++) pp[u] = *(const unsigned*)(lst + 2 * (p + u));
        uint2 v[4];
#pragma unroll
        for (int u = 0; u < 4; u++) {
            int s = hi ? (int)(pp[u] >> 16) : (int)(pp[u] & 0xffff);
            v[u] = rows[s * 32 + l31];
        }
#pragma unroll
        for (int u = 0; u < 4; u++) {
            s0 += __uint_as_float(v[u].x << 16);
            s1 += __uint_as_float(v[u].x & 0xffff0000u);
            s2 += __uint_as_float(v[u].y << 16);
            s3 += __uint_as_float(v[u].y & 0xffff0000u);
        }
    }
    for (; p < pairs; p++) {
        unsigned pp = *(const unsigned*)(lst + 2 * p);
        int s = hi ? (int)(pp >> 16) : (int)(pp & 0xffff);
        uint2 vv = rows[s * 32 + l31];
        s0 += __uint_as_float(vv.x << 16);
        s1 += __uint_as_float(vv.x & 0xffff0000u);
        s2 += __uint_as_float(vv.y << 16);
        s3 += __uint_as_float(vv.y & 0xffff0000u);
    }
    if (m & 1) {
        int s = lst[m - 1];
        if (!hi) {
            uint2 vv = rows[s * 32 + l31];
            s0 += __uint_as_float(vv.x << 16);
            s1 += __uint_as_float(vv.x & 0xffff0000u);
            s2 += __uint_as_float(vv.y << 16);
            s3 += __uint_as_float(vv.y & 0xffff0000u);
        }
    }
    s0 += __shfl_xor(s0, 32, 64);
    s1 += __shfl_xor(s1, 32, 64);
    s2 += __shfl_xor(s2, 32, 64);
    s3 += __shfl_xor(s3, 32, 64);
    if (!hi) {
        float invd = 1.0f / fmaxf((float)m, 1.0f);
        uint2 w;
        w.x = pack2(s0 * invd, s1 * invd);
        w.y = pack2(s2 * invd, s3 * invd);
        ((uint2*)neigh)[(size_t)node * 32 + l31] = w;
    }
}

// ================ fused, register-resident B operands:
//   512 threads = 8 waves; wave w owns output cols 16w..16w+15 for BOTH GEMMs.
//   wt B-frags (8) and feaT B-frags (4) loaded ONCE per block into VGPRs.
//   128-row tile streamed as 8 m-tiles of 16 rows; cross-wave softmax via
//   tiny LDS pmax/psum reductions + 4.2KB P round-trip (3 barriers/m-tile).
__global__ __launch_bounds__(512) void fused_kernel(
    const short* __restrict__ h_bf, const short* __restrict__ neigh,
    const short* __restrict__ wt, const float* __restrict__ bias,
    const short* __restrict__ feaT, float* __restrict__ out)
{
    __shared__ __align__(16) short ldsP[16 * 132];   // 4.2 KB
    __shared__ float pmaxLDS[16 * 8];
    __shared__ float psumLDS[16 * 8];

    int tid = threadIdx.x;
    int wave = tid >> 6, lane = tid & 63;
    int l15 = lane & 15, quad = lane >> 4;
    int row0 = blockIdx.x * 128;
    int g = row0 >> 10;               // 8 blocks per graph
    int ncol = wave * 16;             // this wave's output column base

    // ---- B operands, loaded once into registers
    short8 wtB[8];
#pragma unroll
    for (int kk = 0; kk < 8; kk++)
        wtB[kk] = *reinterpret_cast<const short8*>(
            wt + (ncol + l15) * 256 + kk * 32 + quad * 8);
    short8 feaB[4];
#pragma unroll
    for (int ks = 0; ks < 4; ks++)
        feaB[ks] = *reinterpret_cast<const short8*>(
            feaT + ((size_t)g * 128 + ncol + l15) * 128 + ks * 32 + quad * 8);
    float bv = bias[ncol + l15];

    floatx4 zz = {0.f, 0.f, 0.f, 0.f};

    for (int mt = 0; mt < 8; mt++) {
        int mrow = row0 + mt * 16;

        // ---- GEMM1: 16-row x 16-col logits slice, K=256
        short8 af[8];
#pragma unroll
        for (int kk = 0; kk < 8; kk++) {
            const short* ap = (kk < 4)
                ? h_bf + (size_t)(mrow + l15) * DIN + kk * 32 + quad * 8
                : neigh + (size_t)(mrow + l15) * DIN + (kk - 4) * 32 + quad * 8;
            af[kk] = *reinterpret_cast<const short8*>(ap);
        }
        floatx4 acc = zz;
#pragma unroll
        for (int kk = 0; kk < 8; kk++)
            acc = __builtin_amdgcn_mfma_f32_16x16x32_bf16(af[kk], wtB[kk], acc, 0, 0, 0);

        // ---- relu+bias; cross-wave softmax (this wave has 16 of 128 cols)
        float x[4], pm[4];
#pragma unroll
        for (int v = 0; v < 4; v++) {
            float t = fmaxf(acc[v] + bv, 0.f);
            x[v] = t;
            pm[v] = t;
        }
#pragma unroll
        for (int off = 1; off < 16; off <<= 1)
#pragma unroll
            for (int v = 0; v < 4; v++) pm[v] = fmaxf(pm[v], __shfl_xor(pm[v], off, 64));
        if (l15 == 0) {
#pragma unroll
            for (int v = 0; v < 4; v++) pmaxLDS[(quad * 4 + v) * 8 + wave] = pm[v];
        }
        __syncthreads();
        float gm[4];
#pragma unroll
        for (int v = 0; v < 4; v++) {
            int r = quad * 4 + v;
            float a = fmaxf(fmaxf(pmaxLDS[r*8+0], pmaxLDS[r*8+1]),
                            fmaxf(pmaxLDS[r*8+2], pmaxLDS[r*8+3]));
            float b = fmaxf(fmaxf(pmaxLDS[r*8+4], pmaxLDS[r*8+5]),
                            fmaxf(pmaxLDS[r*8+6], pmaxLDS[r*8+7]));
            gm[v] = fmaxf(a, b);
        }
        float ps[4];
#pragma unroll
        for (int v = 0; v < 4; v++) {
            x[v] = __expf(x[v] - gm[v]);
            ps[v] = x[v];
        }
#pragma unroll
        for (int off = 1; off < 16; off <<= 1)
#pragma unroll
            for (int v = 0; v < 4; v++) ps[v] += __shfl_xor(ps[v], off, 64);
        if (l15 == 0) {
#pragma unroll
            for (int v = 0; v < 4; v++) psumLDS[(quad * 4 + v) * 8 + wave] = ps[v];
        }
        __syncthreads();
#pragma unroll
        for (int v = 0; v < 4; v++) {
            int r = quad * 4 + v;
            float s = (psumLDS[r*8+0] + psumLDS[r*8+1] + psumLDS[r*8+2] + psumLDS[r*8+3])
                    + (psumLDS[r*8+4] + psumLDS[r*8+5] + psumLDS[r*8+6] + psumLDS[r*8+7]);
            float inv = 1.0f / s;
            ldsP[r * 132 + ncol + l15] = f2bf(x[v] * inv);
        }
        __syncthreads();

        // ---- GEMM2: out slice = P(16x128) @ feaB(128x16)
        short8 pf[4];
#pragma unroll
        for (int ks = 0; ks < 4; ks++)
            pf[ks] = *reinterpret_cast<const short8*>(
                ldsP + l15 * 132 + ks * 32 + quad * 8);
        floatx4 oacc = zz;
#pragma unroll
        for (int ks = 0; ks < 4; ks++)
            oacc = __builtin_amdgcn_mfma_f32_16x16x32_bf16(pf[ks], feaB[ks], oacc, 0, 0, 0);

#pragma unroll
        for (int v = 0; v < 4; v++) {
            int row = mrow + quad * 4 + v;
            out[(size_t)row * 128 + ncol + l15] = oacc[v];
        }
    }
}

extern "C" void kernel_launch(void* const* d_in, const int* in_sizes, int n_in,
                              void* d_out, int out_size, void* d_ws, size_t ws_size,
                              hipStream_t stream) {
    const float* h      = (const float*)d_in[0];
    const float* fea    = (const float*)d_in[1];
    const float* Wself  = (const float*)d_in[2];
    const float* Wneigh = (const float*)d_in[3];
    const float* bias   = (const float*)d_in[4];
    const int*   esrc   = (const int*)d_in[5];
    const int*   edst   = (const int*)d_in[6];
    float* out = (float*)d_out;

    char* ws = (char*)d_ws;
    short* h_bf = (short*)ws;
    size_t off = (size_t)N_NODES * DIN * sizeof(short);                       // 16 MB
    short* neigh = (short*)(ws + off); off += (size_t)N_NODES * DIN * sizeof(short);   // 16 MB
    short* wt    = (short*)(ws + off); off += (size_t)128 * 256 * sizeof(short);       // 64 KB
    short* feaT  = (short*)(ws + off); off += (size_t)B_G * 128 * 128 * sizeof(short); // 2 MB
    unsigned short* csr = (unsigned short*)(ws + off); off += (size_t)B_G * CSTRIDE * sizeof(short); // 2.2 MB
    int* offs = (int*)(ws + off); off += (size_t)N_NODES * sizeof(int);       // 256 KB
    int* deg  = (int*)(ws + off); off += (size_t)N_NODES * sizeof(int);       // 256 KB
    int* slicecnt  = (int*)(ws + off); off += (size_t)B_G * NSLICE * NPG * sizeof(int); // 2 MB
    int* sliceoffs = (int*)(ws + off);                                        // 2 MB

    // setup_a grid: 512 hist blocks + (32768 + 1048576 + 1048576)/256 = 8320 conv blocks
    setup_a<<<B_G * NSLICE + 8320, 256, 0, stream>>>(Wself, Wneigh, fea, h, edst,
                                                     wt, feaT, h_bf, slicecnt);
    setup_b<<<B_G, 1024, 0, stream>>>(slicecnt, offs, deg, sliceoffs);
    setup_c<<<B_G * NSLICE, 256, 0, stream>>>(esrc, edst, sliceoffs, csr);
    agg_kernel<<<256 * B_G, 256, 0, stream>>>(h_bf, csr, offs, deg, neigh);
    fused_kernel<<<N_NODES / 128, 512, 0, stream>>>(h_bf, neigh, wt, bias, feaT, out);
}

// Round 7
// 182.740 us; speedup vs baseline: 1.1016x; 1.0846x over previous
//
#include <hip/hip_runtime.h>

#define N_NODES 65536
#define B_G     64
#define NPG     1024
#define KC      128
#define DIN     128
#define E_EDGES 1048576
#define EPG     16384
#define NSLICE  8
#define SLICE_E (EPG / NSLICE)    // 2048 edges per slice
#define CSTRIDE (EPG + NPG)       // per-graph CSR slots (even-padded offsets)

typedef __attribute__((ext_vector_type(8))) short short8;
typedef __attribute__((ext_vector_type(4))) float floatx4;

static __device__ __forceinline__ short f2bf(float x) {
    unsigned u = __float_as_uint(x);
    unsigned r = (u + 0x7FFF + ((u >> 16) & 1)) >> 16;
    return (short)r;
}
static __device__ __forceinline__ unsigned pack2(float a, float b) {
    return (unsigned)(unsigned short)f2bf(a) | ((unsigned)(unsigned short)f2bf(b) << 16);
}

// ================ setup_a: blocks 0..511 = per-(graph,slice) degree histogram;
//                  blocks 512.. = wt / feaT / h_bf conversions
__global__ __launch_bounds__(256) void setup_a(
    const float* __restrict__ Wself, const float* __restrict__ Wneigh,
    const float* __restrict__ fea, const float* __restrict__ h,
    const int* __restrict__ edst,
    short* __restrict__ wt, short* __restrict__ feaT, short* __restrict__ h_bf,
    int* __restrict__ slicecnt)
{
    int bid = blockIdx.x;
    int tid = threadIdx.x;
    if (bid < B_G * NSLICE) {
        __shared__ int cnt[NPG];
        int g = bid >> 3, s = bid & 7;
        int gbase = g << 10;
        for (int i = tid; i < NPG; i += 256) cnt[i] = 0;
        __syncthreads();
        const int* ed = edst + (size_t)g * EPG + s * SLICE_E;
#pragma unroll
        for (int it = 0; it < SLICE_E / 256; it++)
            atomicAdd(&cnt[ed[it * 256 + tid] - gbase], 1);
        __syncthreads();
        int* sc = slicecnt + ((size_t)bid << 10);
        for (int i = tid; i < NPG; i += 256) sc[i] = cnt[i];
    } else {
        long idx = (long)(bid - B_G * NSLICE) * 256 + tid;
        if (idx < 32768) {
            int n = (int)(idx >> 8), k = (int)(idx & 255);
            float v = (k < 128) ? Wself[k * 128 + n] : Wneigh[(k - 128) * 128 + n];
            wt[idx] = f2bf(v);
        } else if (idx < 32768 + 1048576) {
            long fi = idx - 32768;
            int g = (int)(fi >> 14), d = (int)((fi >> 7) & 127), k = (int)(fi & 127);
            feaT[fi] = f2bf(fea[((long)g * 128 + k) * 128 + d]);
        } else {
            long gi = idx - 32768 - 1048576;   // 8 floats per item
            const float4* hp = (const float4*)h + gi * 2;
            float4 a = hp[0], b4 = hp[1];
            uint4 w;
            w.x = pack2(a.x, a.y);
            w.y = pack2(a.z, a.w);
            w.z = pack2(b4.x, b4.y);
            w.w = pack2(b4.z, b4.w);
            ((uint4*)h_bf)[gi] = w;
        }
    }
}

// ================ setup_b: per-graph scan -> offs, deg, per-slice bases
__global__ __launch_bounds__(1024) void setup_b(
    const int* __restrict__ slicecnt, int* __restrict__ offs,
    int* __restrict__ deg, int* __restrict__ sliceoffs)
{
    __shared__ int sa[NPG];
    int g = blockIdx.x;
    int tid = threadIdx.x;
    int s8[NSLICE];
    int d = 0;
#pragma unroll
    for (int s = 0; s < NSLICE; s++) {
        s8[s] = slicecnt[(((size_t)g * NSLICE + s) << 10) + tid];
        d += s8[s];
    }
    int p = (d + 1) & ~1;
    sa[tid] = p;
    __syncthreads();
    for (int off = 1; off < NPG; off <<= 1) {
        int v = sa[tid];
        int vv = (tid >= off) ? sa[tid - off] : 0;
        __syncthreads();
        sa[tid] = v + vv;
        __syncthreads();
    }
    int excl = sa[tid] - p;
    offs[(g << 10) + tid] = excl;
    deg[(g << 10) + tid] = d;
    int run = excl;
#pragma unroll
    for (int s = 0; s < NSLICE; s++) {
        sliceoffs[(((size_t)g * NSLICE + s) << 10) + tid] = run;
        run += s8[s];
    }
}

// ================ setup_c: per-(graph,slice) scatter into CSR
__global__ __launch_bounds__(256) void setup_c(
    const int* __restrict__ esrc, const int* __restrict__ edst,
    const int* __restrict__ sliceoffs, unsigned short* __restrict__ csr)
{
    __shared__ int cur[NPG];
    int bid = blockIdx.x;
    int tid = threadIdx.x;
    int g = bid >> 3, s = bid & 7;
    int gbase = g << 10;
    const int* so = sliceoffs + ((size_t)bid << 10);
    for (int i = tid; i < NPG; i += 256) cur[i] = so[i];
    __syncthreads();
    const int* ed = edst + (size_t)g * EPG + s * SLICE_E;
    const int* es = esrc + (size_t)g * EPG + s * SLICE_E;
    unsigned short* cg = csr + (size_t)g * CSTRIDE;
#pragma unroll
    for (int it = 0; it < SLICE_E / 256; it++) {
        int e = it * 256 + tid;
        int d = ed[e] - gbase;
        int src = es[e] - gbase;
        int pos = atomicAdd(&cur[d], 1);
        cg[pos] = (unsigned short)src;
    }
}

// ================ aggregation (pull, bf16): one wave per node,
// 2 edges per gather instruction (lanes 0-31 edge A, 32-63 edge B).
__global__ __launch_bounds__(256) void agg_kernel(
    const short* __restrict__ h_bf, const unsigned short* __restrict__ csr,
    const int* __restrict__ offs, const int* __restrict__ deg,
    short* __restrict__ neigh)
{
    int g = blockIdx.x >> 8;          // 256 chunks per graph, contiguous
    int chunk = blockIdx.x & 255;
    int wave = threadIdx.x >> 6, lane = threadIdx.x & 63;
    int local = chunk * 4 + wave;
    int node = g * NPG + local;
    int start = offs[node];
    int m = deg[node];
    const unsigned short* lst = csr + (size_t)g * CSTRIDE + start;
    const uint2* rows = (const uint2*)h_bf + (size_t)g * NPG * 32;  // 32 uint2 / row
    int l31 = lane & 31;
    int hi = lane >> 5;
    float s0 = 0.f, s1 = 0.f, s2 = 0.f, s3 = 0.f;
    int pairs = m >> 1;
    int p = 0;
    for (; p + 4 <= pairs; p += 4) {
        unsigned pp[4];
#pragma unroll
        for (int u = 0; u < 4; u++) pp[u] = *(const unsigned*)(lst + 2 * (p + u));
        uint2 v[4];
#pragma unroll
        for (int u = 0; u < 4; u++) {
            int s = hi ? (int)(pp[u] >> 16) : (int)(pp[u] & 0xffff);
            v[u] = rows[s * 32 + l31];
        }
#pragma unroll
        for (int u = 0; u < 4; u++) {
            s0 += __uint_as_float(v[u].x << 16);
            s1 += __uint_as_float(v[u].x & 0xffff0000u);
            s2 += __uint_as_float(v[u].y << 16);
            s3 += __uint_as_float(v[u].y & 0xffff0000u);
        }
    }
    for (; p < pairs; p++) {
        unsigned pp = *(const unsigned*)(lst + 2 * p);
        int s = hi ? (int)(pp >> 16) : (int)(pp & 0xffff);
        uint2 vv = rows[s * 32 + l31];
        s0 += __uint_as_float(vv.x << 16);
        s1 += __uint_as_float(vv.x & 0xffff0000u);
        s2 += __uint_as_float(vv.y << 16);
        s3 += __uint_as_float(vv.y & 0xffff0000u);
    }
    if (m & 1) {
        int s = lst[m - 1];
        if (!hi) {
            uint2 vv = rows[s * 32 + l31];
            s0 += __uint_as_float(vv.x << 16);
            s1 += __uint_as_float(vv.x & 0xffff0000u);
            s2 += __uint_as_float(vv.y << 16);
            s3 += __uint_as_float(vv.y & 0xffff0000u);
        }
    }
    s0 += __shfl_xor(s0, 32, 64);
    s1 += __shfl_xor(s1, 32, 64);
    s2 += __shfl_xor(s2, 32, 64);
    s3 += __shfl_xor(s3, 32, 64);
    if (!hi) {
        float invd = 1.0f / fmaxf((float)m, 1.0f);
        uint2 w;
        w.x = pack2(s0 * invd, s1 * invd);
        w.y = pack2(s2 * invd, s3 * invd);
        ((uint2*)neigh)[(size_t)node * 32 + l31] = w;
    }
}

// ================ fused v5: B-operands staged in LDS once per block.
//   256 thr / 128-row tile / grid 512.  LDS = 2 x [128][132] bf16 = 67.6 KB.
//   Region W: wt k-half1, later feaT.   Region Y: wt k-half2, later P.
//   3 barriers total; A-fragments stream direct from global.
__global__ __launch_bounds__(256) void fused_kernel(
    const short* __restrict__ h_bf, const short* __restrict__ neigh,
    const short* __restrict__ wt, const float* __restrict__ bias,
    const short* __restrict__ feaT, float* __restrict__ out)
{
    __shared__ __align__(16) short ldsW[128 * 132];   // 33.8 KB
    __shared__ __align__(16) short ldsY[128 * 132];   // 33.8 KB

    int tid = threadIdx.x;
    int tile_m = blockIdx.x * 128;
    int g = tile_m >> 10;
    int wave = tid >> 6, lane = tid & 63;
    int l15 = lane & 15, quad = lane >> 4;

    int wrow = tid >> 1;              // staging: 0..127
    int wcol = (tid & 1) * 64;        // staging: 0 or 64

    // ---- stage wt into LDS: half1 (k 0..127) -> W, half2 (k 128..255) -> Y
    {
        const short* s1 = wt + wrow * 256 + wcol;
        const short* s2 = wt + wrow * 256 + 128 + wcol;
        short* d1 = ldsW + wrow * 132 + wcol;
        short* d2 = ldsY + wrow * 132 + wcol;
        short8 t1[8], t2[8];
#pragma unroll
        for (int i = 0; i < 8; i++) t1[i] = *reinterpret_cast<const short8*>(s1 + i * 8);
#pragma unroll
        for (int i = 0; i < 8; i++) t2[i] = *reinterpret_cast<const short8*>(s2 + i * 8);
#pragma unroll
        for (int i = 0; i < 8; i++) *reinterpret_cast<short8*>(d1 + i * 8) = t1[i];
#pragma unroll
        for (int i = 0; i < 8; i++) *reinterpret_cast<short8*>(d2 + i * 8) = t2[i];
    }
    __syncthreads();   // barrier 1: wt staged

    floatx4 zz = {0.f, 0.f, 0.f, 0.f};
    floatx4 acc[2][8];
#pragma unroll
    for (int i = 0; i < 2; i++)
#pragma unroll
        for (int j = 0; j < 8; j++) acc[i][j] = zz;

    // ---- GEMM1: logits = [h_bf | neigh] @ wt^T; A direct-global, B from LDS
#pragma unroll
    for (int kk = 0; kk < 4; kk++) {
#pragma unroll
        for (int ks = 0; ks < 2; ks++) {
            int colk = kk * 64 + ks * 32 + quad * 8;
            short8 af[2];
#pragma unroll
            for (int rb = 0; rb < 2; rb++) {
                int m = tile_m + wave * 32 + rb * 16 + l15;
                af[rb] = (kk < 2)
                    ? *reinterpret_cast<const short8*>(h_bf + (size_t)m * DIN + colk)
                    : *reinterpret_cast<const short8*>(neigh + (size_t)m * DIN + (colk - 128));
            }
            const short* bbase = (kk < 2) ? (ldsW + (colk))
                                          : (ldsY + (colk - 128));
#pragma unroll
            for (int cb = 0; cb < 8; cb++) {
                int n = cb * 16 + l15;
                short8 bf = *reinterpret_cast<const short8*>(bbase + n * 132);
                acc[0][cb] = __builtin_amdgcn_mfma_f32_16x16x32_bf16(af[0], bf, acc[0][cb], 0, 0, 0);
                acc[1][cb] = __builtin_amdgcn_mfma_f32_16x16x32_bf16(af[1], bf, acc[1][cb], 0, 0, 0);
            }
        }
    }
    __syncthreads();   // barrier 2: all wt LDS reads done; W/Y reusable

    // ---- issue feaT staging loads FIRST (latency hides under softmax VALU)
    short8 ft[8];
    {
        const short* sf = feaT + ((size_t)g * 128 + wrow) * 128 + wcol;
#pragma unroll
        for (int i = 0; i < 8; i++) ft[i] = *reinterpret_cast<const short8*>(sf + i * 8);
    }

    // ---- softmax(relu(+bias)) in regs; P -> ldsY (stride 132)
    float bv[8];
#pragma unroll
    for (int cb = 0; cb < 8; cb++) bv[cb] = bias[cb * 16 + l15];

#pragma unroll
    for (int rb = 0; rb < 2; rb++) {
#pragma unroll
        for (int v = 0; v < 4; v++) {
            float x[8];
            float m = -1e30f;
#pragma unroll
            for (int cb = 0; cb < 8; cb++) {
                float t = acc[rb][cb][v] + bv[cb];
                t = fmaxf(t, 0.f);
                x[cb] = t;
                m = fmaxf(m, t);
            }
#pragma unroll
            for (int off = 1; off < 16; off <<= 1) m = fmaxf(m, __shfl_xor(m, off, 64));
            float s = 0.f;
#pragma unroll
            for (int cb = 0; cb < 8; cb++) { x[cb] = __expf(x[cb] - m); s += x[cb]; }
#pragma unroll
            for (int off = 1; off < 16; off <<= 1) s += __shfl_xor(s, off, 64);
            float inv = 1.0f / s;
            int row = wave * 32 + rb * 16 + quad * 4 + v;   // local row
#pragma unroll
            for (int cb = 0; cb < 8; cb++)
                ldsY[row * 132 + cb * 16 + l15] = f2bf(x[cb] * inv);
        }
    }

    // ---- write staged feaT into W
    {
        short* df = ldsW + wrow * 132 + wcol;
#pragma unroll
        for (int i = 0; i < 8; i++) *reinterpret_cast<short8*>(df + i * 8) = ft[i];
    }
    __syncthreads();   // barrier 3: P + feaT staged

    // ---- GEMM2: out = P @ fea[g], both operands from LDS
    floatx4 oacc[2][8];
#pragma unroll
    for (int i = 0; i < 2; i++)
#pragma unroll
        for (int j = 0; j < 8; j++) oacc[i][j] = zz;

    short8 pf[2][4];
#pragma unroll
    for (int rb = 0; rb < 2; rb++)
#pragma unroll
        for (int ks = 0; ks < 4; ks++)
            pf[rb][ks] = *reinterpret_cast<const short8*>(
                ldsY + (wave * 32 + rb * 16 + l15) * 132 + ks * 32 + quad * 8);

#pragma unroll
    for (int cb = 0; cb < 8; cb++) {
#pragma unroll
        for (int ks = 0; ks < 4; ks++) {
            short8 bf = *reinterpret_cast<const short8*>(
                ldsW + (cb * 16 + l15) * 132 + ks * 32 + quad * 8);
            oacc[0][cb] = __builtin_amdgcn_mfma_f32_16x16x32_bf16(pf[0][ks], bf, oacc[0][cb], 0, 0, 0);
            oacc[1][cb] = __builtin_amdgcn_mfma_f32_16x16x32_bf16(pf[1][ks], bf, oacc[1][cb], 0, 0, 0);
        }
    }

#pragma unroll
    for (int rb = 0; rb < 2; rb++)
#pragma unroll
        for (int v = 0; v < 4; v++) {
            int row = tile_m + wave * 32 + rb * 16 + quad * 4 + v;
#pragma unroll
            for (int cb = 0; cb < 8; cb++)
                out[(size_t)row * 128 + cb * 16 + l15] = oacc[rb][cb][v];
        }
}

extern "C" void kernel_launch(void* const* d_in, const int* in_sizes, int n_in,
                              void* d_out, int out_size, void* d_ws, size_t ws_size,
                              hipStream_t stream) {
    const float* h      = (const float*)d_in[0];
    const float* fea    = (const float*)d_in[1];
    const float* Wself  = (const float*)d_in[2];
    const float* Wneigh = (const float*)d_in[3];
    const float* bias   = (const float*)d_in[4];
    const int*   esrc   = (const int*)d_in[5];
    const int*   edst   = (const int*)d_in[6];
    float* out = (float*)d_out;

    char* ws = (char*)d_ws;
    short* h_bf = (short*)ws;
    size_t off = (size_t)N_NODES * DIN * sizeof(short);                       // 16 MB
    short* neigh = (short*)(ws + off); off += (size_t)N_NODES * DIN * sizeof(short);   // 16 MB
    short* wt    = (short*)(ws + off); off += (size_t)128 * 256 * sizeof(short);       // 64 KB
    short* feaT  = (short*)(ws + off); off += (size_t)B_G * 128 * 128 * sizeof(short); // 2 MB
    unsigned short* csr = (unsigned short*)(ws + off); off += (size_t)B_G * CSTRIDE * sizeof(short); // 2.2 MB
    int* offs = (int*)(ws + off); off += (size_t)N_NODES * sizeof(int);       // 256 KB
    int* deg  = (int*)(ws + off); off += (size_t)N_NODES * sizeof(int);       // 256 KB
    int* slicecnt  = (int*)(ws + off); off += (size_t)B_G * NSLICE * NPG * sizeof(int); // 2 MB
    int* sliceoffs = (int*)(ws + off);                                        // 2 MB

    // setup_a grid: 512 hist blocks + (32768 + 1048576 + 1048576)/256 = 8320 conv blocks
    setup_a<<<B_G * NSLICE + 8320, 256, 0, stream>>>(Wself, Wneigh, fea, h, edst,
                                                     wt, feaT, h_bf, slicecnt);
    setup_b<<<B_G, 1024, 0, stream>>>(slicecnt, offs, deg, sliceoffs);
    setup_c<<<B_G * NSLICE, 256, 0, stream>>>(esrc, edst, sliceoffs, csr);
    agg_kernel<<<256 * B_G, 256, 0, stream>>>(h_bf, csr, offs, deg, neigh);
    fused_kernel<<<N_NODES / 128, 256, 0, stream>>>(h_bf, neigh, wt, bias, feaT, out);
}

// Round 8
// 175.990 us; speedup vs baseline: 1.1439x; 1.0384x over previous
//
#include <hip/hip_runtime.h>

#define N_NODES 65536
#define B_G     64
#define NPG     1024
#define KC      128
#define DIN     128
#define E_EDGES 1048576
#define EPG     16384
#define NSLICE  8
#define SLICE_E (EPG / NSLICE)    // 2048 edges per slice
#define CSTRIDE (EPG + NPG)       // per-graph CSR slots (even-padded offsets)

typedef __attribute__((ext_vector_type(8))) short short8;
typedef __attribute__((ext_vector_type(4))) float floatx4;

static __device__ __forceinline__ short f2bf(float x) {
    unsigned u = __float_as_uint(x);
    unsigned r = (u + 0x7FFF + ((u >> 16) & 1)) >> 16;
    return (short)r;
}
static __device__ __forceinline__ unsigned pack2(float a, float b) {
    return (unsigned)(unsigned short)f2bf(a) | ((unsigned)(unsigned short)f2bf(b) << 16);
}

// ================ setup_a: blocks 0..511 = per-(graph,slice) degree histogram;
//                  blocks 512.. = wt / feaT / h_bf conversions
__global__ __launch_bounds__(256) void setup_a(
    const float* __restrict__ Wself, const float* __restrict__ Wneigh,
    const float* __restrict__ fea, const float* __restrict__ h,
    const int* __restrict__ edst,
    short* __restrict__ wt, short* __restrict__ feaT, short* __restrict__ h_bf,
    int* __restrict__ slicecnt)
{
    int bid = blockIdx.x;
    int tid = threadIdx.x;
    if (bid < B_G * NSLICE) {
        __shared__ int cnt[NPG];
        int g = bid >> 3, s = bid & 7;
        int gbase = g << 10;
        for (int i = tid; i < NPG; i += 256) cnt[i] = 0;
        __syncthreads();
        const int* ed = edst + (size_t)g * EPG + s * SLICE_E;
#pragma unroll
        for (int it = 0; it < SLICE_E / 256; it++)
            atomicAdd(&cnt[ed[it * 256 + tid] - gbase], 1);
        __syncthreads();
        int* sc = slicecnt + ((size_t)bid << 10);
        for (int i = tid; i < NPG; i += 256) sc[i] = cnt[i];
    } else {
        long idx = (long)(bid - B_G * NSLICE) * 256 + tid;
        if (idx < 32768) {
            int n = (int)(idx >> 8), k = (int)(idx & 255);
            float v = (k < 128) ? Wself[k * 128 + n] : Wneigh[(k - 128) * 128 + n];
            wt[idx] = f2bf(v);
        } else if (idx < 32768 + 1048576) {
            long fi = idx - 32768;
            int g = (int)(fi >> 14), d = (int)((fi >> 7) & 127), k = (int)(fi & 127);
            feaT[fi] = f2bf(fea[((long)g * 128 + k) * 128 + d]);
        } else {
            long gi = idx - 32768 - 1048576;   // 8 floats per item
            const float4* hp = (const float4*)h + gi * 2;
            float4 a = hp[0], b4 = hp[1];
            uint4 w;
            w.x = pack2(a.x, a.y);
            w.y = pack2(a.z, a.w);
            w.z = pack2(b4.x, b4.y);
            w.w = pack2(b4.z, b4.w);
            ((uint4*)h_bf)[gi] = w;
        }
    }
}

// ================ setup_c (scan merged in): per-(graph,slice) scatter into CSR.
//   Each block redundantly computes the per-graph padded exclusive scan from
//   slicecnt (coalesced 16 KB read), derives its own slice's cur[] bases, and
//   the s==0 block writes offs/deg.  Replaces the old setup_b launch + the
//   4 MB sliceoffs round-trip.
__global__ __launch_bounds__(256) void setup_c(
    const int* __restrict__ esrc, const int* __restrict__ edst,
    const int* __restrict__ slicecnt,
    int* __restrict__ offs, int* __restrict__ deg,
    unsigned short* __restrict__ csr)
{
    __shared__ int sa[256];
    __shared__ int cur[NPG];
    int bid = blockIdx.x;
    int tid = threadIdx.x;
    int g = bid >> 3, s = bid & 7;
    int gbase = g << 10;

    // ---- load 8 slices x 4 bins; accumulate totals + own-slice prefix
    int dsum[4] = {0, 0, 0, 0};
    int myexcl[4] = {0, 0, 0, 0};
#pragma unroll
    for (int ss = 0; ss < NSLICE; ss++) {
        const int* scp = slicecnt + (((size_t)g * NSLICE + ss) << 10);
#pragma unroll
        for (int j = 0; j < 4; j++) {
            int v = scp[tid * 4 + j];
            dsum[j] += v;
            if (ss < s) myexcl[j] += v;
        }
    }
    int p[4];
    int local = 0;
#pragma unroll
    for (int j = 0; j < 4; j++) {
        p[j] = (dsum[j] + 1) & ~1;     // pad per-node slot count to even
        local += p[j];
    }
    sa[tid] = local;
    __syncthreads();
    for (int off = 1; off < 256; off <<= 1) {
        int v = sa[tid];
        int vv = (tid >= off) ? sa[tid - off] : 0;
        __syncthreads();
        sa[tid] = v + vv;
        __syncthreads();
    }
    int run = sa[tid] - local;         // exclusive padded prefix (even)
#pragma unroll
    for (int j = 0; j < 4; j++) {
        int i = tid * 4 + j;
        if (s == 0) {
            offs[gbase + i] = run;
            deg[gbase + i] = dsum[j];
        }
        cur[i] = run + myexcl[j];
        run += p[j];
    }
    __syncthreads();

    // ---- scatter this slice's edges
    const int* ed = edst + (size_t)g * EPG + s * SLICE_E;
    const int* es = esrc + (size_t)g * EPG + s * SLICE_E;
    unsigned short* cg = csr + (size_t)g * CSTRIDE;
#pragma unroll
    for (int it = 0; it < SLICE_E / 256; it++) {
        int e = it * 256 + tid;
        int d = ed[e] - gbase;
        int src = es[e] - gbase;
        int pos = atomicAdd(&cur[d], 1);
        cg[pos] = (unsigned short)src;
    }
}

// ================ aggregation (pull, bf16): one wave per node,
// 2 edges per gather instruction (lanes 0-31 edge A, 32-63 edge B)
__global__ __launch_bounds__(256) void agg_kernel(
    const short* __restrict__ h_bf, const unsigned short* __restrict__ csr,
    const int* __restrict__ offs, const int* __restrict__ deg,
    short* __restrict__ neigh)
{
    int g = blockIdx.x & 63;
    int chunk = blockIdx.x >> 6;
    int wave = threadIdx.x >> 6, lane = threadIdx.x & 63;
    int local = chunk * 4 + wave;
    int node = g * NPG + local;
    int start = offs[node];
    int m = deg[node];
    const unsigned short* lst = csr + (size_t)g * CSTRIDE + start;
    const uint2* rows = (const uint2*)h_bf + (size_t)g * NPG * 32;  // 32 uint2 / row
    int l31 = lane & 31;
    int hi = lane >> 5;
    float s0 = 0.f, s1 = 0.f, s2 = 0.f, s3 = 0.f;
    int pairs = m >> 1;
    int p = 0;
    for (; p + 4 <= pairs; p += 4) {
        unsigned pp[4];
#pragma unroll
        for (int u = 0; u < 4; u++) pp[u] = *(const unsigned*)(lst + 2 * (p + u));
        uint2 v[4];
#pragma unroll
        for (int u = 0; u < 4; u++) {
            int s = hi ? (int)(pp[u] >> 16) : (int)(pp[u] & 0xffff);
            v[u] = rows[s * 32 + l31];
        }
#pragma unroll
        for (int u = 0; u < 4; u++) {
            s0 += __uint_as_float(v[u].x << 16);
            s1 += __uint_as_float(v[u].x & 0xffff0000u);
            s2 += __uint_as_float(v[u].y << 16);
            s3 += __uint_as_float(v[u].y & 0xffff0000u);
        }
    }
    for (; p < pairs; p++) {
        unsigned pp = *(const unsigned*)(lst + 2 * p);
        int s = hi ? (int)(pp >> 16) : (int)(pp & 0xffff);
        uint2 vv = rows[s * 32 + l31];
        s0 += __uint_as_float(vv.x << 16);
        s1 += __uint_as_float(vv.x & 0xffff0000u);
        s2 += __uint_as_float(vv.y << 16);
        s3 += __uint_as_float(vv.y & 0xffff0000u);
    }
    if (m & 1) {
        int s = lst[m - 1];
        if (!hi) {
            uint2 vv = rows[s * 32 + l31];
            s0 += __uint_as_float(vv.x << 16);
            s1 += __uint_as_float(vv.x & 0xffff0000u);
            s2 += __uint_as_float(vv.y << 16);
            s3 += __uint_as_float(vv.y & 0xffff0000u);
        }
    }
    s0 += __shfl_xor(s0, 32, 64);
    s1 += __shfl_xor(s1, 32, 64);
    s2 += __shfl_xor(s2, 32, 64);
    s3 += __shfl_xor(s3, 32, 64);
    if (!hi) {
        float invd = 1.0f / fmaxf((float)m, 1.0f);
        uint2 w;
        w.x = pack2(s0 * invd, s1 * invd);
        w.y = pack2(s2 * invd, s3 * invd);
        ((uint2*)neigh)[(size_t)node * 32 + l31] = w;
    }
}

// ================ fused: assign = softmax(relu([h_bf|neigh] @ wt^T + b));
//                  out = assign @ fea   (P kept on-chip via LDS round-trip)
__global__ __launch_bounds__(256) void fused_kernel(
    const short* __restrict__ h_bf, const short* __restrict__ neigh,
    const short* __restrict__ wt, const float* __restrict__ bias,
    const short* __restrict__ feaT, float* __restrict__ out)
{
    __shared__ __align__(16) char smem[50688];
    short* lds_a = (short*)smem;            // phase1: 128x72
    short* lds_b = lds_a + 128 * 72;        // phase1: 128x72
    short* ldsP  = (short*)smem;            // phase2: 128x132 (overlaps phase1)
    short* ldsB2 = ldsP + 128 * 132;        // phase2: 64x132

    int tid = threadIdx.x;
    int tile_m = blockIdx.x * 128;
    int g = tile_m >> 10;
    int wave = tid >> 6, lane = tid & 63;
    int l15 = lane & 15, quad = lane >> 4;

    floatx4 zz = {0.f, 0.f, 0.f, 0.f};
    floatx4 acc[2][8];
#pragma unroll
    for (int i = 0; i < 2; i++)
#pragma unroll
        for (int j = 0; j < 8; j++) acc[i][j] = zz;

    int row_s = tid >> 1;
    int c0 = (tid & 1) * 32;

    // ---- GEMM1: logits = [h_bf | neigh] @ wt^T, K=256 in 4 chunks of 64
    for (int kk = 0; kk < 4; kk++) {
        const short* src = (kk < 2)
            ? h_bf + (size_t)(tile_m + row_s) * DIN + kk * 64 + c0
            : neigh + (size_t)(tile_m + row_s) * DIN + (kk - 2) * 64 + c0;
        short* dsta = lds_a + row_s * 72 + c0;
#pragma unroll
        for (int i = 0; i < 32; i += 8)
            *reinterpret_cast<short8*>(dsta + i) = *reinterpret_cast<const short8*>(src + i);
        const short* srcb = wt + row_s * 256 + kk * 64 + c0;
        short* dstb = lds_b + row_s * 72 + c0;
#pragma unroll
        for (int i = 0; i < 32; i += 8)
            *reinterpret_cast<short8*>(dstb + i) = *reinterpret_cast<const short8*>(srcb + i);
        __syncthreads();
#pragma unroll
        for (int ks = 0; ks < 2; ks++) {
            short8 af[2];
#pragma unroll
            for (int rb = 0; rb < 2; rb++) {
                int m = wave * 32 + rb * 16 + l15;
                af[rb] = *reinterpret_cast<const short8*>(lds_a + m * 72 + ks * 32 + quad * 8);
            }
#pragma unroll
            for (int cb = 0; cb < 8; cb++) {
                int n = cb * 16 + l15;
                short8 bf = *reinterpret_cast<const short8*>(lds_b + n * 72 + ks * 32 + quad * 8);
                acc[0][cb] = __builtin_amdgcn_mfma_f32_16x16x32_bf16(af[0], bf, acc[0][cb], 0, 0, 0);
                acc[1][cb] = __builtin_amdgcn_mfma_f32_16x16x32_bf16(af[1], bf, acc[1][cb], 0, 0, 0);
            }
        }
        __syncthreads();
    }

    // ---- softmax(relu(+bias)) in regs; P -> LDS (bf16, stride 132)
    float bv[8];
#pragma unroll
    for (int cb = 0; cb < 8; cb++) bv[cb] = bias[cb * 16 + l15];

#pragma unroll
    for (int rb = 0; rb < 2; rb++) {
#pragma unroll
        for (int v = 0; v < 4; v++) {
            float x[8];
            float m = -1e30f;
#pragma unroll
            for (int cb = 0; cb < 8; cb++) {
                float t = acc[rb][cb][v] + bv[cb];
                t = fmaxf(t, 0.f);
                x[cb] = t;
                m = fmaxf(m, t);
            }
#pragma unroll
            for (int off = 1; off < 16; off <<= 1) m = fmaxf(m, __shfl_xor(m, off, 64));
            float s = 0.f;
#pragma unroll
            for (int cb = 0; cb < 8; cb++) { x[cb] = __expf(x[cb] - m); s += x[cb]; }
#pragma unroll
            for (int off = 1; off < 16; off <<= 1) s += __shfl_xor(s, off, 64);
            float inv = 1.0f / s;
            int row = wave * 32 + rb * 16 + quad * 4 + v;   // local row
#pragma unroll
            for (int cb = 0; cb < 8; cb++)
                ldsP[row * 132 + cb * 16 + l15] = f2bf(x[cb] * inv);
        }
    }

    // ---- GEMM2: out = P @ fea[g], feaT staged in two 64-row halves
    floatx4 oacc[2][8];
#pragma unroll
    for (int i = 0; i < 2; i++)
#pragma unroll
        for (int j = 0; j < 8; j++) oacc[i][j] = zz;

    int r2 = tid >> 2;            // 0..63
    int c2 = (tid & 3) * 32;      // 0..96
    short8 pf[2][4];

    for (int half = 0; half < 2; half++) {
        if (half) __syncthreads();   // protect previous-half B reads
        const short* srcb = feaT + ((size_t)g * 128 + half * 64 + r2) * 128 + c2;
        short* dstb = ldsB2 + r2 * 132 + c2;
#pragma unroll
        for (int i = 0; i < 32; i += 8)
            *reinterpret_cast<short8*>(dstb + i) = *reinterpret_cast<const short8*>(srcb + i);
        __syncthreads();
        if (half == 0) {
#pragma unroll
            for (int rb = 0; rb < 2; rb++)
#pragma unroll
                for (int ks = 0; ks < 4; ks++)
                    pf[rb][ks] = *reinterpret_cast<const short8*>(
                        ldsP + (wave * 32 + rb * 16 + l15) * 132 + ks * 32 + quad * 8);
        }
#pragma unroll
        for (int cb2 = 0; cb2 < 4; cb2++) {
            int cb = half * 4 + cb2;
#pragma unroll
            for (int ks = 0; ks < 4; ks++) {
                short8 bf = *reinterpret_cast<const short8*>(
                    ldsB2 + (cb2 * 16 + l15) * 132 + ks * 32 + quad * 8);
                oacc[0][cb] = __builtin_amdgcn_mfma_f32_16x16x32_bf16(pf[0][ks], bf, oacc[0][cb], 0, 0, 0);
                oacc[1][cb] = __builtin_amdgcn_mfma_f32_16x16x32_bf16(pf[1][ks], bf, oacc[1][cb], 0, 0, 0);
            }
        }
    }

#pragma unroll
    for (int rb = 0; rb < 2; rb++)
#pragma unroll
        for (int v = 0; v < 4; v++) {
            int row = tile_m + wave * 32 + rb * 16 + quad * 4 + v;
#pragma unroll
            for (int cb = 0; cb < 8; cb++)
                out[(size_t)row * 128 + cb * 16 + l15] = oacc[rb][cb][v];
        }
}

extern "C" void kernel_launch(void* const* d_in, const int* in_sizes, int n_in,
                              void* d_out, int out_size, void* d_ws, size_t ws_size,
                              hipStream_t stream) {
    const float* h      = (const float*)d_in[0];
    const float* fea    = (const float*)d_in[1];
    const float* Wself  = (const float*)d_in[2];
    const float* Wneigh = (const float*)d_in[3];
    const float* bias   = (const float*)d_in[4];
    const int*   esrc   = (const int*)d_in[5];
    const int*   edst   = (const int*)d_in[6];
    float* out = (float*)d_out;

    char* ws = (char*)d_ws;
    short* h_bf = (short*)ws;
    size_t off = (size_t)N_NODES * DIN * sizeof(short);                       // 16 MB
    short* neigh = (short*)(ws + off); off += (size_t)N_NODES * DIN * sizeof(short);   // 16 MB
    short* wt    = (short*)(ws + off); off += (size_t)128 * 256 * sizeof(short);       // 64 KB
    short* feaT  = (short*)(ws + off); off += (size_t)B_G * 128 * 128 * sizeof(short); // 2 MB
    unsigned short* csr = (unsigned short*)(ws + off); off += (size_t)B_G * CSTRIDE * sizeof(short); // 2.2 MB
    int* offs = (int*)(ws + off); off += (size_t)N_NODES * sizeof(int);       // 256 KB
    int* deg  = (int*)(ws + off); off += (size_t)N_NODES * sizeof(int);       // 256 KB
    int* slicecnt = (int*)(ws + off);                                         // 2 MB

    // setup_a grid: 512 hist blocks + (32768 + 1048576 + 1048576)/256 = 8320 conv blocks
    setup_a<<<B_G * NSLICE + 8320, 256, 0, stream>>>(Wself, Wneigh, fea, h, edst,
                                                     wt, feaT, h_bf, slicecnt);
    setup_c<<<B_G * NSLICE, 256, 0, stream>>>(esrc, edst, slicecnt, offs, deg, csr);
    agg_kernel<<<256 * B_G, 256, 0, stream>>>(h_bf, csr, offs, deg, neigh);
    fused_kernel<<<N_NODES / 128, 256, 0, stream>>>(h_bf, neigh, wt, bias, feaT, out);
}